// Round 1
// baseline (8377.825 us; speedup 1.0000x reference)
//
#include <hip/hip_runtime.h>
#include <hip/hip_bf16.h>

// GraphCNN fused per-graph kernel — Round 0 baseline (fp32 vector ALU).
// One workgroup per graph; adj staged in LDS as bf16 (rounds to nearest via
// +0x8000), all intermediates ([90,128] fp32) live in LDS; output Z=Y@Y^T
// written once. Total LDS ~153 KB (needs gfx950 160 KB workgroup LDS).
// Roofline: 164.5 GFLOP total; fp32-vector floor ~1.05 ms. MFMA rewrite is
// the planned round-1+ direction (~85 us balanced roofline).

#define NN 90
#define NP 96        // padded adj row stride (bf16 elems) -> 16B-aligned rows
#define HH 128
#define NT 256
#define RPT 45       // (NN*HH)/NT outputs per thread (rows i0, i0+2, ...)

static __device__ __forceinline__ void bf2x2(unsigned int pk, float& lo, float& hi) {
    union { unsigned int u; float f; } a, b;
    a.u = pk << 16;
    b.u = pk & 0xffff0000u;
    lo = a.f; hi = b.f;
}

__global__ __launch_bounds__(NT) void graphcnn_kernel(
    const float* __restrict__ adj,
    const float* __restrict__ W0,  const float* __restrict__ b0,
    const float* __restrict__ W1,  const float* __restrict__ b1,
    const float* __restrict__ W2,  const float* __restrict__ b2,
    const float* __restrict__ Wr1, const float* __restrict__ br1,
    const float* __restrict__ Wr2, const float* __restrict__ br2,
    float* __restrict__ out)
{
    __shared__ __align__(16) unsigned short sAdj[NN * NP];  // 17,280 B (bf16 bits)
    __shared__ __align__(16) float sP[NN * HH];             // 46,080 B  h0 -> u -> Y
    __shared__ __align__(16) float sQ[NN * 130];            // 46,800 B  t -> x -> skewed Y
    __shared__ __align__(16) float sR[NN * HH];             // 46,080 B  r1

    const int b  = blockIdx.x;
    const int t  = threadIdx.x;
    const int c  = t & (HH - 1);   // hidden column owned by this thread
    const int i0 = t >> 7;         // row parity: rows i0, i0+2, ..., i0+88

    // ---- stage adj -> LDS bf16 (round-half-up) ----
    const float* Ag = adj + (size_t)b * (NN * NN);
    for (int idx = t; idx < NN * NN; idx += NT) {
        const int i = idx / NN;
        const int j = idx - i * NN;
        sAdj[i * NP + j] = (unsigned short)((__float_as_uint(Ag[idx]) + 0x8000u) >> 16);
    }
    __syncthreads();

    float acc[RPT];

    // acc[r] += sum_j adj[i0+2r, j] * B(j)   (B(j) supplies B[j, c])
    auto adj_mm = [&](auto Bread) {
        for (int jc = 0; jc < 11; jc++) {          // j = 0..87 in chunks of 8
            float w[8];
            #pragma unroll
            for (int u = 0; u < 8; u++) w[u] = Bread(jc * 8 + u);
            #pragma unroll
            for (int r = 0; r < RPT; r++) {
                const uint4 pk = *(const uint4*)&sAdj[(i0 + 2 * r) * NP + jc * 8];
                float a0,a1,a2,a3,a4,a5,a6,a7;
                bf2x2(pk.x,a0,a1); bf2x2(pk.y,a2,a3);
                bf2x2(pk.z,a4,a5); bf2x2(pk.w,a6,a7);
                acc[r] += a0*w[0] + a1*w[1] + a2*w[2] + a3*w[3]
                        + a4*w[4] + a5*w[5] + a6*w[6] + a7*w[7];
            }
        }
        {   // tail j = 88, 89
            const float w0v = Bread(88), w1v = Bread(89);
            #pragma unroll
            for (int r = 0; r < RPT; r++) {
                const unsigned int pk = *(const unsigned int*)&sAdj[(i0 + 2 * r) * NP + 88];
                float a0, a1; bf2x2(pk, a0, a1);
                acc[r] += a0 * w0v + a1 * w1v;
            }
        }
    };

    // acc[r] += sum_k A[i0+2r, k] * W[k, c]   (A = LDS [NN][HH], W global)
    auto lin_mm = [&](const float* Asrc, const float* __restrict__ Wsrc) {
        for (int kc = 0; kc < 32; kc++) {
            float w[4];
            #pragma unroll
            for (int u = 0; u < 4; u++) w[u] = Wsrc[(kc * 4 + u) * HH + c];
            #pragma unroll
            for (int r = 0; r < RPT; r++) {
                const float4 av = *(const float4*)&Asrc[(i0 + 2 * r) * HH + kc * 4];
                acc[r] += av.x*w[0] + av.y*w[1] + av.z*w[2] + av.w*w[3];
            }
        }
    };

    // ===== Step 1: h0 = adj @ W0 + b0 -> sP =====
    {
        const float bb = b0[c];
        #pragma unroll
        for (int r = 0; r < RPT; r++) acc[r] = bb;
        adj_mm([&](int j) { return W0[j * HH + c]; });
        #pragma unroll
        for (int r = 0; r < RPT; r++) sP[(i0 + 2 * r) * HH + c] = acc[r];
    }
    __syncthreads();

    // ===== Step 2: r1 = h0 @ Wr1 + br1 -> sR =====
    {
        const float bb = br1[c];
        #pragma unroll
        for (int r = 0; r < RPT; r++) acc[r] = bb;
        lin_mm(sP, Wr1);
        #pragma unroll
        for (int r = 0; r < RPT; r++) sR[(i0 + 2 * r) * HH + c] = acc[r];
    }
    __syncthreads();

    // ===== Step 3: tmat = adj @ h0 -> sQ =====
    {
        #pragma unroll
        for (int r = 0; r < RPT; r++) acc[r] = 0.f;
        adj_mm([&](int j) { return sP[j * HH + c]; });
        #pragma unroll
        for (int r = 0; r < RPT; r++) sQ[(i0 + 2 * r) * HH + c] = acc[r];
    }
    __syncthreads();

    // ===== Step 4: x = relu(tmat @ W1 + b1) + r1 -> sQ (in place) =====
    {
        const float bb = b1[c];
        #pragma unroll
        for (int r = 0; r < RPT; r++) acc[r] = bb;
        lin_mm(sQ, W1);
        __syncthreads();   // everyone done reading tmat
        #pragma unroll
        for (int r = 0; r < RPT; r++) {
            const int ii = (i0 + 2 * r) * HH + c;
            sQ[ii] = fmaxf(acc[r], 0.f) + sR[ii];
        }
    }
    __syncthreads();

    // ===== Step 5: u = adj @ x -> sP (h0 dead) =====
    {
        #pragma unroll
        for (int r = 0; r < RPT; r++) acc[r] = 0.f;
        adj_mm([&](int j) { return sQ[j * HH + c]; });
        #pragma unroll
        for (int r = 0; r < RPT; r++) sP[(i0 + 2 * r) * HH + c] = acc[r];
    }
    __syncthreads();

    // ===== Step 6: Y = relu(u @ W2 + b2 + r1 @ Wr2 + br2) -> sP (in place) =====
    {
        const float bb = b2[c] + br2[c];
        #pragma unroll
        for (int r = 0; r < RPT; r++) acc[r] = bb;
        lin_mm(sP, W2);    // u @ W2
        lin_mm(sR, Wr2);   // r1 @ Wr2
        __syncthreads();   // everyone done reading u
        #pragma unroll
        for (int r = 0; r < RPT; r++) {
            sP[(i0 + 2 * r) * HH + c] = fmaxf(acc[r], 0.f);
        }
    }
    __syncthreads();

    // ===== Step 7: Z = Y @ Y^T -> out =====
    // Skewed copy (stride 129) so the j-parallel reads spread across banks.
    for (int idx = t; idx < NN * HH; idx += NT) {
        const int i = idx >> 7, k = idx & (HH - 1);
        sQ[i * 129 + k] = sP[idx];
    }
    __syncthreads();

    float* outb = out + (size_t)b * (NN * NN);
    for (int q = t; q < 45 * 45; q += NT) {
        const int qi = q / 45;
        const int qj = q - qi * 45;
        const int i1 = qi, i2 = qi + 45;
        const int j1 = qj, j2 = qj + 45;
        float a11 = 0.f, a12 = 0.f, a21 = 0.f, a22 = 0.f;
        #pragma unroll 8
        for (int k = 0; k < HH; k++) {
            const float yi1 = sP[i1 * HH + k], yi2 = sP[i2 * HH + k];
            const float yj1 = sQ[j1 * 129 + k], yj2 = sQ[j2 * 129 + k];
            a11 += yi1 * yj1; a12 += yi1 * yj2;
            a21 += yi2 * yj1; a22 += yi2 * yj2;
        }
        outb[i1 * NN + j1] = a11; outb[i1 * NN + j2] = a12;
        outb[i2 * NN + j1] = a21; outb[i2 * NN + j2] = a22;
    }
}

extern "C" void kernel_launch(void* const* d_in, const int* in_sizes, int n_in,
                              void* d_out, int out_size, void* d_ws, size_t ws_size,
                              hipStream_t stream) {
    const float* adj = (const float*)d_in[0];
    const float* W0  = (const float*)d_in[1];
    const float* b0  = (const float*)d_in[2];
    const float* W1  = (const float*)d_in[3];
    const float* b1  = (const float*)d_in[4];
    const float* W2  = (const float*)d_in[5];
    const float* b2  = (const float*)d_in[6];
    const float* Wr1 = (const float*)d_in[7];
    const float* br1 = (const float*)d_in[8];
    const float* Wr2 = (const float*)d_in[9];
    const float* br2 = (const float*)d_in[10];
    float* out = (float*)d_out;

    const int B = in_sizes[0] / (NN * NN);
    graphcnn_kernel<<<B, NT, 0, stream>>>(adj, W0, b0, W1, b1, W2, b2,
                                          Wr1, br1, Wr2, br2, out);
}

// Round 2
// 819.697 us; speedup vs baseline: 10.2206x; 10.2206x over previous
//
#include <hip/hip_runtime.h>
#include <hip/hip_bf16.h>

// GraphCNN fused per-graph MFMA kernel (fp16 inputs, fp32 accumulate).
// One workgroup (256 thr = 4 waves) per graph. All intermediates in LDS fp16.
// mfma_f32_32x32x16_f16; A-operand buffers row-major stride 136 (bank-optimal),
// B-operand buffers transposed stride 104 (bank-optimal). Weights pre-converted
// + transposed to fp16 in d_ws by prep kernel. LDS total 98,816 B -> 1 block/CU.
//
// MFMA layouts (gfx950, verified learn_hip m74/m101/m120):
//   A: A[m][k], m = lane&31, k = (lane>>5)*8 + j   (8 contiguous k -> b128)
//   B: B[k][n], n = lane&31, k = (lane>>5)*8 + j
//   C/D: col = lane&31, row = (reg&3) + 8*(reg>>2) + 4*(lane>>5)

#define NN 90
#define HH 128
#define NT 256

typedef _Float16 half8 __attribute__((ext_vector_type(8)));
typedef _Float16 half4 __attribute__((ext_vector_type(4)));
typedef float floatx16 __attribute__((ext_vector_type(16)));

#define SR 136      // row-major (A-layout) stride, f16 elems; 96 rows
#define SR8 17      // SR/8
#define ST 104      // transposed (B-layout) + adj stride; bank-shift 20 dw (optimal)
#define ST8 13      // ST/8
#define ST4 26      // ST/4

#define MFMA(a, b, c) __builtin_amdgcn_mfma_f32_32x32x16_f16((a), (b), (c), 0, 0, 0)

// ---------------- weight prep: fp32 -> fp16, transposed ----------------
// ws layout (f16): W0T [128][96] @0 ; Wr1T, W1T, W2T, Wr2T [128][128] after.
__global__ void prep_weights(const float* __restrict__ W0,
                             const float* __restrict__ Wr1,
                             const float* __restrict__ W1,
                             const float* __restrict__ W2,
                             const float* __restrict__ Wr2,
                             _Float16* __restrict__ ws)
{
    const int idx = blockIdx.x * blockDim.x + threadIdx.x;
    if (idx >= 77824) return;
    if (idx < 12288) {                       // W0T[n][k], k padded 90->96 w/ zeros
        const int n = idx / 96, k = idx - n * 96;
        ws[idx] = (k < NN) ? (_Float16)W0[k * HH + n] : (_Float16)0.f;
    } else {
        const int j = idx - 12288;
        const int m = j >> 14;               // which 128x128 matrix
        const int r = j & 16383;
        const int n = r >> 7, k = r & 127;
        const float* src = (m == 0) ? Wr1 : (m == 1) ? W1 : (m == 2) ? W2 : Wr2;
        ws[idx] = (_Float16)src[k * HH + n];
    }
}

// ---------------- main fused kernel ----------------
__global__ __launch_bounds__(NT) void graphcnn_mfma(
    const float* __restrict__ adj,
    const _Float16* __restrict__ wts,
    const float* __restrict__ b0, const float* __restrict__ b1,
    const float* __restrict__ b2, const float* __restrict__ br1,
    const float* __restrict__ br2,
    float* __restrict__ out)
{
    // LDS: adjH [96][104] f16 | bufA [96][136] (h0R->tR->uR) |
    //      bufT [128][104] (h0T->xT) reused as YR [96][136] | r1R [96][136]
    __shared__ __align__(16) unsigned char smem[98816];
    _Float16* adjH = (_Float16*)smem;
    _Float16* bufA = (_Float16*)(smem + 19968);
    _Float16* bufT = (_Float16*)(smem + 46080);
    _Float16* r1R  = (_Float16*)(smem + 72704);

    const int t    = threadIdx.x;
    const int wv   = t >> 6;
    const int lane = t & 63;
    const int p    = lane & 31;
    const int h    = lane >> 5;
    const int n    = wv * 32 + p;      // hidden column owned in steps 1-6

    const _Float16* W0T  = wts;                 // [128][96]
    const _Float16* Wr1T = wts + 12288;         // [128][128]
    const _Float16* W1T  = Wr1T + 16384;
    const _Float16* W2T  = W1T + 16384;
    const _Float16* Wr2T = W2T + 16384;

    // ---- zero adjH (pads must be finite-zero), then stage adj fp32->fp16 ----
    for (int i = t; i < (96 * ST) / 2; i += NT) ((unsigned int*)adjH)[i] = 0u;
    __syncthreads();
    const float* Ag = adj + (size_t)blockIdx.x * (NN * NN);
    for (int i = t; i < NN * NN; i += NT) {
        const int r = i / NN, c = i - r * NN;
        adjH[r * ST + c] = (_Float16)Ag[i];
    }
    __syncthreads();

    // C-register -> LDS writers
    auto writeR = [&](_Float16* buf, int mt, int col, const floatx16& A) {
        #pragma unroll
        for (int r = 0; r < 16; r++) {
            const int node = mt * 32 + (r & 3) + 8 * (r >> 2) + 4 * h;
            buf[node * SR + col] = (_Float16)A[r];
        }
    };
    auto writeT = [&](_Float16* buf, int mt, int col, const floatx16& A) {
        #pragma unroll
        for (int rg = 0; rg < 4; rg++) {
            half4 v = { (_Float16)A[4*rg], (_Float16)A[4*rg+1],
                        (_Float16)A[4*rg+2], (_Float16)A[4*rg+3] };
            ((half4*)buf)[col * ST4 + mt * 8 + 2 * rg + h] = v;
        }
    };

    floatx16 acc0, acc1, acc2;

    // ===== S1: h0 = adj @ W0 + b0  -> bufA (R) and bufT (T) =====
    {
        half8 bf[6];
        #pragma unroll
        for (int kt = 0; kt < 6; kt++) bf[kt] = ((const half8*)W0T)[n * 12 + kt * 2 + h];
        const float bias = b0[n];
        #pragma unroll
        for (int r = 0; r < 16; r++) { acc0[r] = bias; acc1[r] = bias; acc2[r] = bias; }
        #pragma unroll
        for (int kt = 0; kt < 6; kt++) {
            half8 a0 = ((const half8*)adjH)[(0 * 32 + p) * ST8 + kt * 2 + h];
            half8 a1 = ((const half8*)adjH)[(1 * 32 + p) * ST8 + kt * 2 + h];
            half8 a2 = ((const half8*)adjH)[(2 * 32 + p) * ST8 + kt * 2 + h];
            acc0 = MFMA(a0, bf[kt], acc0);
            acc1 = MFMA(a1, bf[kt], acc1);
            acc2 = MFMA(a2, bf[kt], acc2);
        }
        writeR(bufA, 0, n, acc0); writeR(bufA, 1, n, acc1); writeR(bufA, 2, n, acc2);
        writeT(bufT, 0, n, acc0); writeT(bufT, 1, n, acc1); writeT(bufT, 2, n, acc2);
    }
    __syncthreads();

    // ===== S2: r1 = h0R @ Wr1 + br1 -> r1R =====
    {
        half8 bf[8];
        #pragma unroll
        for (int kt = 0; kt < 8; kt++) bf[kt] = ((const half8*)Wr1T)[n * 16 + kt * 2 + h];
        const float bias = br1[n];
        #pragma unroll
        for (int r = 0; r < 16; r++) { acc0[r] = bias; acc1[r] = bias; acc2[r] = bias; }
        #pragma unroll
        for (int kt = 0; kt < 8; kt++) {
            half8 a0 = ((const half8*)bufA)[(0 * 32 + p) * SR8 + kt * 2 + h];
            half8 a1 = ((const half8*)bufA)[(1 * 32 + p) * SR8 + kt * 2 + h];
            half8 a2 = ((const half8*)bufA)[(2 * 32 + p) * SR8 + kt * 2 + h];
            acc0 = MFMA(a0, bf[kt], acc0);
            acc1 = MFMA(a1, bf[kt], acc1);
            acc2 = MFMA(a2, bf[kt], acc2);
        }
        writeR(r1R, 0, n, acc0); writeR(r1R, 1, n, acc1); writeR(r1R, 2, n, acc2);
    }
    __syncthreads();

    // ===== S3: t = adj @ h0 (B from bufT) -> bufA (R) =====
    {
        #pragma unroll
        for (int r = 0; r < 16; r++) { acc0[r] = 0.f; acc1[r] = 0.f; acc2[r] = 0.f; }
        #pragma unroll
        for (int kt = 0; kt < 6; kt++) {
            half8 bfk = ((const half8*)bufT)[n * ST8 + kt * 2 + h];
            half8 a0 = ((const half8*)adjH)[(0 * 32 + p) * ST8 + kt * 2 + h];
            half8 a1 = ((const half8*)adjH)[(1 * 32 + p) * ST8 + kt * 2 + h];
            half8 a2 = ((const half8*)adjH)[(2 * 32 + p) * ST8 + kt * 2 + h];
            acc0 = MFMA(a0, bfk, acc0);
            acc1 = MFMA(a1, bfk, acc1);
            acc2 = MFMA(a2, bfk, acc2);
        }
        writeR(bufA, 0, n, acc0); writeR(bufA, 1, n, acc1); writeR(bufA, 2, n, acc2);
    }
    __syncthreads();

    // ===== S4: x = relu(t @ W1 + b1) + r1 -> bufT (T) =====
    {
        half8 bf[8];
        #pragma unroll
        for (int kt = 0; kt < 8; kt++) bf[kt] = ((const half8*)W1T)[n * 16 + kt * 2 + h];
        const float bias = b1[n];
        #pragma unroll
        for (int r = 0; r < 16; r++) { acc0[r] = bias; acc1[r] = bias; acc2[r] = bias; }
        #pragma unroll
        for (int kt = 0; kt < 8; kt++) {
            half8 a0 = ((const half8*)bufA)[(0 * 32 + p) * SR8 + kt * 2 + h];
            half8 a1 = ((const half8*)bufA)[(1 * 32 + p) * SR8 + kt * 2 + h];
            half8 a2 = ((const half8*)bufA)[(2 * 32 + p) * SR8 + kt * 2 + h];
            acc0 = MFMA(a0, bf[kt], acc0);
            acc1 = MFMA(a1, bf[kt], acc1);
            acc2 = MFMA(a2, bf[kt], acc2);
        }
        #pragma unroll
        for (int mt = 0; mt < 3; mt++) {
            floatx16& A = (mt == 0) ? acc0 : (mt == 1) ? acc1 : acc2;
            floatx16 xv;
            #pragma unroll
            for (int r = 0; r < 16; r++) {
                const int node = mt * 32 + (r & 3) + 8 * (r >> 2) + 4 * h;
                xv[r] = fmaxf(A[r], 0.f) + (float)r1R[node * SR + n];
            }
            writeT(bufT, mt, n, xv);
        }
    }
    __syncthreads();

    // ===== S5: u = adj @ x (B from bufT) -> bufA (R) =====
    {
        #pragma unroll
        for (int r = 0; r < 16; r++) { acc0[r] = 0.f; acc1[r] = 0.f; acc2[r] = 0.f; }
        #pragma unroll
        for (int kt = 0; kt < 6; kt++) {
            half8 bfk = ((const half8*)bufT)[n * ST8 + kt * 2 + h];
            half8 a0 = ((const half8*)adjH)[(0 * 32 + p) * ST8 + kt * 2 + h];
            half8 a1 = ((const half8*)adjH)[(1 * 32 + p) * ST8 + kt * 2 + h];
            half8 a2 = ((const half8*)adjH)[(2 * 32 + p) * ST8 + kt * 2 + h];
            acc0 = MFMA(a0, bfk, acc0);
            acc1 = MFMA(a1, bfk, acc1);
            acc2 = MFMA(a2, bfk, acc2);
        }
        writeR(bufA, 0, n, acc0); writeR(bufA, 1, n, acc1); writeR(bufA, 2, n, acc2);
    }
    __syncthreads();

    // ===== S6: Y = relu(u@W2 + r1@Wr2 + b2 + br2) -> YR (bufT region, R) =====
    {
        half8 bf[8];
        #pragma unroll
        for (int kt = 0; kt < 8; kt++) bf[kt] = ((const half8*)W2T)[n * 16 + kt * 2 + h];
        const float bias = b2[n] + br2[n];
        #pragma unroll
        for (int r = 0; r < 16; r++) { acc0[r] = bias; acc1[r] = bias; acc2[r] = bias; }
        #pragma unroll
        for (int kt = 0; kt < 8; kt++) {
            half8 a0 = ((const half8*)bufA)[(0 * 32 + p) * SR8 + kt * 2 + h];
            half8 a1 = ((const half8*)bufA)[(1 * 32 + p) * SR8 + kt * 2 + h];
            half8 a2 = ((const half8*)bufA)[(2 * 32 + p) * SR8 + kt * 2 + h];
            acc0 = MFMA(a0, bf[kt], acc0);
            acc1 = MFMA(a1, bf[kt], acc1);
            acc2 = MFMA(a2, bf[kt], acc2);
        }
        half8 bg[8];
        #pragma unroll
        for (int kt = 0; kt < 8; kt++) bg[kt] = ((const half8*)Wr2T)[n * 16 + kt * 2 + h];
        #pragma unroll
        for (int kt = 0; kt < 8; kt++) {
            half8 a0 = ((const half8*)r1R)[(0 * 32 + p) * SR8 + kt * 2 + h];
            half8 a1 = ((const half8*)r1R)[(1 * 32 + p) * SR8 + kt * 2 + h];
            half8 a2 = ((const half8*)r1R)[(2 * 32 + p) * SR8 + kt * 2 + h];
            acc0 = MFMA(a0, bg[kt], acc0);
            acc1 = MFMA(a1, bg[kt], acc1);
            acc2 = MFMA(a2, bg[kt], acc2);
        }
        _Float16* YR = bufT;
        #pragma unroll
        for (int mt = 0; mt < 3; mt++) {
            floatx16& A = (mt == 0) ? acc0 : (mt == 1) ? acc1 : acc2;
            #pragma unroll
            for (int r = 0; r < 16; r++) {
                const int node = mt * 32 + (r & 3) + 8 * (r >> 2) + 4 * h;
                YR[node * SR + n] = (_Float16)fmaxf(A[r], 0.f);
            }
        }
    }
    __syncthreads();

    // ===== S7: Z = Y @ Y^T -> out (both operands from YR, R layout) =====
    {
        const _Float16* YR = bufT;
        float* outb = out + (size_t)blockIdx.x * (NN * NN);
        auto ztile = [&](int mt, int nt) {
            floatx16 acc;
            #pragma unroll
            for (int r = 0; r < 16; r++) acc[r] = 0.f;
            #pragma unroll
            for (int kt = 0; kt < 8; kt++) {
                half8 av = ((const half8*)YR)[(mt * 32 + p) * SR8 + kt * 2 + h];
                half8 bv = ((const half8*)YR)[(nt * 32 + p) * SR8 + kt * 2 + h];
                acc = MFMA(av, bv, acc);
            }
            const int col = nt * 32 + p;
            if (col < NN) {
                #pragma unroll
                for (int r = 0; r < 16; r++) {
                    const int row = mt * 32 + (r & 3) + 8 * (r >> 2) + 4 * h;
                    if (row < NN) outb[row * NN + col] = acc[r];
                }
            }
        };
        if      (wv == 0) { ztile(0, 0); ztile(0, 1); ztile(0, 2); }
        else if (wv == 1) { ztile(1, 0); ztile(1, 1); }
        else if (wv == 2) { ztile(1, 2); ztile(2, 0); }
        else              { ztile(2, 1); ztile(2, 2); }
    }
}

extern "C" void kernel_launch(void* const* d_in, const int* in_sizes, int n_in,
                              void* d_out, int out_size, void* d_ws, size_t ws_size,
                              hipStream_t stream) {
    const float* adj = (const float*)d_in[0];
    const float* W0  = (const float*)d_in[1];
    const float* b0  = (const float*)d_in[2];
    const float* W1  = (const float*)d_in[3];
    const float* b1  = (const float*)d_in[4];
    const float* W2  = (const float*)d_in[5];
    const float* b2  = (const float*)d_in[6];
    const float* Wr1 = (const float*)d_in[7];
    const float* br1 = (const float*)d_in[8];
    const float* Wr2 = (const float*)d_in[9];
    const float* br2 = (const float*)d_in[10];
    float* out = (float*)d_out;
    _Float16* wts = (_Float16*)d_ws;

    prep_weights<<<76, 1024, 0, stream>>>(W0, Wr1, W1, W2, Wr2, wts);

    const int B = in_sizes[0] / (NN * NN);
    graphcnn_mfma<<<B, NT, 0, stream>>>(adj, wts, b0, b1, b2, br1, br2, out);
}